// Round 4
// baseline (45.558 us; speedup 1.0000x reference)
//
#include <hip/hip_runtime.h>
#include <math.h>

// M is (64, 512, 28, 28) fp32.
#define BB 64
#define CC 512
#define HWP 784                 // 28*28 px per map
#define NF2 392                 // float2 groups per map
#define NCHUNK 16               // channel chunks (32 ch each)
#define NPIX4 12544             // (64*784)/4
#define NPIX2 25088             // (64*784)/2
#define PLANE2 401408           // float2 per plane (16 chunks * 25088)
#define DIS_SLOTS 4096          // 64 b * 16 chunks * 4 waves
#define DIV_SLOTS 196
#define NEG_FILL -999999.0f
#define NTOT 25690112.0         // 64*512*28*28

static __device__ __forceinline__ unsigned sortable(float v) {
  unsigned b = __float_as_uint(v);
  return (b & 0x80000000u) ? ~b : (b | 0x80000000u);
}
// branchless top-2 insert
static __device__ __forceinline__ void top2(float v, float& v1, float& v2) {
  float lo = fminf(v, v1);
  v1 = fmaxf(v1, v);
  v2 = fmaxf(v2, lo);
}
// merge two (v1>=v2) pairs
static __device__ __forceinline__ void mergev(float& v1, float& v2, float b1, float b2) {
  float lo = fminf(v1, b1);
  v1 = fmaxf(v1, b1);
  v2 = fmaxf(lo, fmaxf(v2, b2));
}

// ---------------- fused single-pass kernel ----------------
// block = (chunk, b): 32 ch x 784 px; 4 waves, 8 ch/wave.
// Software-pipelined float2 passes: 6 uniform + 1 masked-uniform tail.
__global__ __launch_bounds__(256, 4) void fused_kernel(const float* __restrict__ M,
    double* __restrict__ slots, float2* __restrict__ wsV1,
    float2* __restrict__ wsV2, float2* __restrict__ wsS) {
  const int lane  = threadIdx.x & 63;
  const int w     = threadIdx.x >> 6;
  const int chunk = blockIdx.x;
  const int b     = blockIdx.y;
  const float2* base2 =
      (const float2*)(M + ((size_t)b * CC + chunk * 32 + w * 8) * HWP);

  float s0[8], sy[8], sx[8], bv[8];
  int bi[8];
  #pragma unroll
  for (int c = 0; c < 8; ++c) { s0[c]=0.f; sy[c]=0.f; sx[c]=0.f; bv[c]=-INFINITY; bi[c]=0; }
  float srr = 0.f;                         // sum of M*(y^2+x^2), lane slice

  __shared__ float2 lm[4][3][NF2];         // per-wave per-pixel (v1,v2,S) : 37632 B

  float2 d[8], dn[8];
  const int f2m = (lane < 8) ? (384 + lane) : 390;   // tail load addr (clamped, in-bounds)

  #pragma unroll
  for (int c = 0; c < 8; ++c) d[c] = base2[c * NF2 + lane];   // prologue: pass 0

  auto consume = [&](int f2pos, bool masked) {
    const int y  = f2pos / 14;             // 2 px per group, 14 groups per row
    const int x0 = (f2pos - y * 14) * 2;
    const float fy  = (float)y;
    const float fx0 = (float)x0, fx1 = fx0 + 1.f;
    const float fyy = fy * fy;
    const float rr0 = fyy + fx0 * fx0, rr1 = fyy + fx1 * fx1;
    const int pxb = f2pos * 2;
    const bool fake = masked && (lane >= 8);

    float v1a = -INFINITY, v2a = -INFINITY, Sa = 0.f;
    float v1b = -INFINITY, v2b = -INFINITY, Sb = 0.f;
    #pragma unroll
    for (int c = 0; c < 8; ++c) {
      float a0 = d[c].x, a1 = d[c].y;      // sum path
      float c0 = a0,     c1 = a1;          // compare path
      if (masked && fake) { a0 = 0.f; a1 = 0.f; c0 = -INFINITY; c1 = -INFINITY; }
      const float sum2 = a0 + a1;
      s0[c] += sum2;
      sy[c] = fmaf(sum2, fy, sy[c]);
      sx[c] = fmaf(a0, fx0, sx[c]); sx[c] = fmaf(a1, fx1, sx[c]);
      srr   = fmaf(a0, rr0, srr);   srr   = fmaf(a1, rr1, srr);
      if (c0 > bv[c]) { bv[c] = c0; bi[c] = pxb;     }
      if (c1 > bv[c]) { bv[c] = c1; bi[c] = pxb + 1; }
      top2(c0, v1a, v2a); Sa += a0;
      top2(c1, v1b, v2b); Sb += a1;
    }
    if (!masked || lane < 8) {
      lm[w][0][f2pos] = make_float2(v1a, v1b);
      lm[w][1][f2pos] = make_float2(v2a, v2b);
      lm[w][2][f2pos] = make_float2(Sa, Sb);
    }
  };

  #pragma unroll
  for (int k = 0; k < 6; ++k) {
    const int nf2 = (k == 5) ? f2m : (lane + 64 * (k + 1));
    #pragma unroll
    for (int c = 0; c < 8; ++c) dn[c] = base2[c * NF2 + nf2];   // prefetch next pass
    consume(lane + 64 * k, false);                               // consume current
    #pragma unroll
    for (int c = 0; c < 8; ++c) d[c] = dn[c];
  }
  consume(384 + lane, true);               // masked-uniform tail pass

  // ---- dis epilogue: per-channel argmax butterfly, lane-local contribution ----
  double dis_acc = (double)srr;
  #pragma unroll
  for (int c = 0; c < 8; ++c) {
    unsigned long long key =
        ((unsigned long long)sortable(bv[c]) << 32) | (unsigned)(~bi[c]);
    #pragma unroll
    for (int off = 1; off < 64; off <<= 1) {
      unsigned long long o = __shfl_xor(key, off);
      key = (key > o) ? key : o;           // max val; tie -> min px
    }
    const int px = (int)(~((unsigned)key));
    const int iy = px / 28;
    const int ix = px - iy * 28;
    dis_acc += (double)s0[c] * (double)(iy * iy + ix * ix)
             - 2.0 * ((double)sy[c] * (double)iy + (double)sx[c] * (double)ix);
  }
  #pragma unroll
  for (int off = 32; off >= 1; off >>= 1)
    dis_acc += __shfl_down(dis_acc, off);
  if (lane == 0)
    slots[((b * NCHUNK + chunk) << 2) | w] = dis_acc;            // unique slot, plain store

  // ---- cross-wave merge of per-pixel top-2 partials ----
  __syncthreads();
  const int t = threadIdx.x;
  #pragma unroll
  for (int rep = 0; rep < 2; ++rep) {
    const int f = t + rep * 256;
    if (f < NF2) {
      float2 mv1 = lm[0][0][f], mv2 = lm[0][1][f], mS = lm[0][2][f];
      #pragma unroll
      for (int ww = 1; ww < 4; ++ww) {
        float2 b1 = lm[ww][0][f], b2 = lm[ww][1][f], bS = lm[ww][2][f];
        mergev(mv1.x, mv2.x, b1.x, b2.x);
        mergev(mv1.y, mv2.y, b1.y, b2.y);
        mS.x += bS.x; mS.y += bS.y;
      }
      const int idx = chunk * NPIX2 + b * NF2 + f;
      wsV1[idx] = mv1; wsV2[idx] = mv2; wsS[idx] = mS;
    }
  }
}

// ---------------- merge chunk partials -> div contribs ----------------
// 196 blocks; wave w folds chunks 4w..4w+3 for 64 f4 pixel-groups; LDS fold.
__global__ __launch_bounds__(256) void div_merge_kernel(const float4* __restrict__ wsV1,
    const float4* __restrict__ wsV2, const float4* __restrict__ wsS,
    double* __restrict__ slots) {
  const int t = threadIdx.x, lane = t & 63, w = t >> 6;
  const int g = blockIdx.x * 64 + lane;

  float4 a1[4], a2[4], aS[4];
  #pragma unroll
  for (int c = 0; c < 4; ++c) {
    const int idx = (w * 4 + c) * NPIX4 + g;
    a1[c] = wsV1[idx]; a2[c] = wsV2[idx]; aS[c] = wsS[idx];
  }
  float4 v1 = a1[0], v2 = a2[0], S = aS[0];
  #pragma unroll
  for (int c = 1; c < 4; ++c) {
    mergev(v1.x, v2.x, a1[c].x, a2[c].x);
    mergev(v1.y, v2.y, a1[c].y, a2[c].y);
    mergev(v1.z, v2.z, a1[c].z, a2[c].z);
    mergev(v1.w, v2.w, a1[c].w, a2[c].w);
    S.x += aS[c].x; S.y += aS[c].y; S.z += aS[c].z; S.w += aS[c].w;
  }
  __shared__ float4 sm[4][3][64];
  sm[w][0][lane] = v1; sm[w][1][lane] = v2; sm[w][2][lane] = S;
  __syncthreads();

  if (t < 64) {
    v1 = sm[0][0][t]; v2 = sm[0][1][t]; S = sm[0][2][t];
    #pragma unroll
    for (int ww = 1; ww < 4; ++ww) {
      mergev(v1.x, v2.x, sm[ww][0][t].x, sm[ww][1][t].x);
      mergev(v1.y, v2.y, sm[ww][0][t].y, sm[ww][1][t].y);
      mergev(v1.z, v2.z, sm[ww][0][t].z, sm[ww][1][t].z);
      mergev(v1.w, v2.w, sm[ww][0][t].w, sm[ww][1][t].w);
      float4 bS = sm[ww][2][t];
      S.x += bS.x; S.y += bS.y; S.z += bS.z; S.w += bS.w;
    }
    // sum_c loo_c*M_c = clamp(v1)*(S - v1) + clamp(v2)*v1  (per pixel)
    double contrib =
        (double)fmaxf(v1.x, NEG_FILL) * ((double)S.x - (double)v1.x) + (double)fmaxf(v2.x, NEG_FILL) * (double)v1.x
      + (double)fmaxf(v1.y, NEG_FILL) * ((double)S.y - (double)v1.y) + (double)fmaxf(v2.y, NEG_FILL) * (double)v1.y
      + (double)fmaxf(v1.z, NEG_FILL) * ((double)S.z - (double)v1.z) + (double)fmaxf(v2.z, NEG_FILL) * (double)v1.z
      + (double)fmaxf(v1.w, NEG_FILL) * ((double)S.w - (double)v1.w) + (double)fmaxf(v2.w, NEG_FILL) * (double)v1.w;
    #pragma unroll
    for (int off = 32; off >= 1; off >>= 1)
      contrib += __shfl_down(contrib, off);
    if (t == 0)
      slots[DIS_SLOTS + blockIdx.x] = contrib;                   // unique slot, plain store
  }
}

// ---------------- finalize: sum 4096 dis + 196 div partials ----------------
__global__ __launch_bounds__(256) void finalize_kernel(const double* __restrict__ slots,
                                                       float* __restrict__ out) {
  const int t = threadIdx.x, lane = t & 63, wv = t >> 6;
  double dis = 0.0;
  #pragma unroll
  for (int i = 0; i < 16; ++i) dis += slots[t + (i << 8)];
  double dv = (t < DIV_SLOTS) ? slots[DIS_SLOTS + t] : 0.0;
  #pragma unroll
  for (int off = 32; off >= 1; off >>= 1) {
    dis += __shfl_down(dis, off);
    dv  += __shfl_down(dv,  off);
  }
  __shared__ double pd[4], pv[4];
  if (lane == 0) { pd[wv] = dis; pv[wv] = dv; }
  __syncthreads();
  if (t == 0) {
    out[0] = (float)((pd[0] + pd[1] + pd[2] + pd[3]) / NTOT);
    out[1] = (float)((pv[0] + pv[1] + pv[2] + pv[3]) / NTOT);
  }
}

extern "C" void kernel_launch(void* const* d_in, const int* in_sizes, int n_in,
                              void* d_out, int out_size, void* d_ws, size_t ws_size,
                              hipStream_t stream) {
  const float* M = (const float*)d_in[0];
  double* slots = (double*)d_ws;                           // 4292 doubles
  float2* planes = (float2*)((char*)d_ws + 65536);         // 3 planes of PLANE2 float2
  float2* wsV1 = planes;
  float2* wsV2 = planes + PLANE2;
  float2* wsS  = planes + 2 * (size_t)PLANE2;
  fused_kernel<<<dim3(NCHUNK, BB), 256, 0, stream>>>(M, slots, wsV1, wsV2, wsS);
  div_merge_kernel<<<DIV_SLOTS, 256, 0, stream>>>(
      (const float4*)wsV1, (const float4*)wsV2, (const float4*)wsS, slots);
  finalize_kernel<<<1, 256, 0, stream>>>(slots, (float*)d_out);
}